// Round 3
// baseline (53.592 us; speedup 1.0000x reference)
//
#include <hip/hip_runtime.h>

#define B 4
#define L 200
#define N 160
#define HS 768
#define HD 256
#define C 16

#define KP 784            // padded K (768 data + 1 gate + 15 zero)
#define WJ 48             // fused output cols: A(16) | B(16) | T(16)
#define KS 4              // split-k slices for the main GEMM
#define KSL (KP / KS)     // 196 k per slice (49 float4 quads)
#define NROW (B * N)      // 640

// ---------------------------------------------------------------------------
// K1, blocks 0..639: hs_s[row, 0:768] = (sum of TO rows for word n) / cnt
//                    hs_s[row, 768]   = (cnt>0)  (gate channel -> bias term)
//                    hs_s[row, 769:784] = 0
//     blocks 640..688: Wfull[k, m*16+c] = sum_d Wd[k,d] * Wc[m*HD+d, c]
//                      Wfull[768, j]    = sum_d bd[d] * Wc[...]   (bias row)
//                      Wfull[769:784,:] = 0
// ---------------------------------------------------------------------------
__global__ __launch_bounds__(256) void prep_kernel(
    const float* __restrict__ TO,      // [B, L+1, HS]
    const float* __restrict__ Wd,      // [HS, HD]
    const float* __restrict__ bd,      // [HD]
    const float* __restrict__ Wc,      // [3*HD, C]
    const int*   __restrict__ wm,      // [B, L]
    const int*   __restrict__ lengths, // [B]
    float* __restrict__ hs_s,          // [NROW, KP]
    float* __restrict__ Wfull)         // [KP, WJ]
{
    const int blk = blockIdx.x;
    const int t = threadIdx.x;

    if (blk < NROW) {
        const int row = blk;
        const int b = row / N, n = row % N;
        const int len = lengths[b];

        __shared__ int smap[L];
        if (t < L) smap[t] = wm[b * L + t];
        __syncthreads();

        int lo = 0, hi = L;
        while (lo < hi) { int m = (lo + hi) >> 1; if (smap[m] < n) lo = m + 1; else hi = m; }
        int lo2 = lo, hi2 = L;
        while (lo2 < hi2) { int m = (lo2 + hi2) >> 1; if (smap[m] < n + 1) lo2 = m + 1; else hi2 = m; }
        const int start = lo < len ? lo : len;
        const int stop  = lo2 < len ? lo2 : len;
        const int cnt   = stop - start;
        const float ci  = (cnt > 0) ? 1.0f / (float)cnt : 0.0f;

        float a0 = 0.f, a1 = 0.f, a2 = 0.f;
        const float* base = TO + ((size_t)b * (L + 1) + 1) * HS;
        for (int l = start; l < stop; ++l) {
            const float* r = base + (size_t)l * HS;
            a0 += r[t]; a1 += r[t + 256]; a2 += r[t + 512];
        }
        float* hr = hs_s + (size_t)row * KP;
        hr[t] = a0 * ci; hr[t + 256] = a1 * ci; hr[t + 512] = a2 * ci;
        if (t < 16) hr[768 + t] = (t == 0 && cnt > 0) ? 1.0f : 0.0f;
    } else {
        const int wb = blk - NROW;     // 0..48
        if (wb < 48) {
            const int kl = t >> 4, c = t & 15;
            const int k = wb * 16 + kl;
            const float4* wd4 = (const float4*)(Wd + (size_t)k * HD);
            float acc0 = 0.f, acc1 = 0.f, acc2 = 0.f;
            #pragma unroll 4
            for (int dq = 0; dq < HD / 4; ++dq) {
                const float4 w = wd4[dq];
                const int d = dq * 4;
                acc0 += w.x * Wc[(0 * HD + d) * C + c]     + w.y * Wc[(0 * HD + d + 1) * C + c]
                      + w.z * Wc[(0 * HD + d + 2) * C + c] + w.w * Wc[(0 * HD + d + 3) * C + c];
                acc1 += w.x * Wc[(1 * HD + d) * C + c]     + w.y * Wc[(1 * HD + d + 1) * C + c]
                      + w.z * Wc[(1 * HD + d + 2) * C + c] + w.w * Wc[(1 * HD + d + 3) * C + c];
                acc2 += w.x * Wc[(2 * HD + d) * C + c]     + w.y * Wc[(2 * HD + d + 1) * C + c]
                      + w.z * Wc[(2 * HD + d + 2) * C + c] + w.w * Wc[(2 * HD + d + 3) * C + c];
            }
            Wfull[(size_t)k * WJ + c]      = acc0;
            Wfull[(size_t)k * WJ + 16 + c] = acc1;
            Wfull[(size_t)k * WJ + 32 + c] = acc2;
        } else {
            // zero pad rows 769..783
            for (int idx = t; idx < 15 * WJ; idx += 256) Wfull[(size_t)769 * WJ + idx] = 0.f;
            if (t < WJ) {   // bias row 768: bd . Wc-block
                const int m = t >> 4, c = t & 15;
                const float4* bd4 = (const float4*)bd;
                float acc = 0.f;
                #pragma unroll 4
                for (int dq = 0; dq < HD / 4; ++dq) {
                    const float4 w = bd4[dq];
                    const int d = dq * 4;
                    acc += w.x * Wc[(m * HD + d) * C + c]     + w.y * Wc[(m * HD + d + 1) * C + c]
                         + w.z * Wc[(m * HD + d + 2) * C + c] + w.w * Wc[(m * HD + d + 3) * C + c];
                }
                Wfull[(size_t)768 * WJ + t] = acc;
            }
        }
    }
}

// ---------------------------------------------------------------------------
// K2: split-k GEMM  part[s, row, j] = sum_{k in slice s} hs_s[row,k]*Wfull[k,j]
//     T cols (j>=32) gated by token mask. 384 thr = 48 j x 8 rows.
// ---------------------------------------------------------------------------
__global__ __launch_bounds__(384) void gemm_kernel(
    const float* __restrict__ hs_s,    // [NROW, KP]
    const float* __restrict__ Wfull,   // [KP, WJ]
    const int*   __restrict__ token_length,
    float* __restrict__ part)          // [KS, NROW, WJ]
{
    const int t  = threadIdx.x;
    const int tj = t % WJ;
    const int tr = t / WJ;
    const int row = blockIdx.y * 8 + tr;
    const int k0  = blockIdx.x * KSL;

    const float* in = hs_s + (size_t)row * KP + k0;
    const float* wf = Wfull + (size_t)k0 * WJ + tj;

    float acc = 0.f;
    #pragma unroll 7
    for (int q = 0; q < KSL / 4; ++q) {
        const float4 v = *(const float4*)(in + 4 * q);
        acc += v.x * wf[(size_t)(4 * q) * WJ]     + v.y * wf[(size_t)(4 * q + 1) * WJ]
             + v.z * wf[(size_t)(4 * q + 2) * WJ] + v.w * wf[(size_t)(4 * q + 3) * WJ];
    }
    const int b = row / N, n = row % N;
    if (tj >= 32 && n >= token_length[b]) acc = 0.f;
    part[((size_t)blockIdx.x * NROW + row) * WJ + tj] = acc;
}

// ---------------------------------------------------------------------------
// K3, blocks 0..19: AB[row, 0:32] = sum_s part[s, row, 0:32]   (A|B reduced)
//     blocks 20..23: S[row, c] = cumsum over n of sum_s part[s, row, 32+c]
// ---------------------------------------------------------------------------
__global__ __launch_bounds__(256) void reduce_scan_kernel(
    const float* __restrict__ part,    // [KS, NROW, WJ]
    float* __restrict__ AB,            // [NROW, 32]
    float* __restrict__ S)             // [NROW, C]
{
    const int blk = blockIdx.x;
    const int t = threadIdx.x;

    if (blk < 20) {
        const int qid = blk * 256 + t;       // 0..5119
        const int row = qid >> 3;
        const int j0  = (qid & 7) * 4;
        float4 s = *(const float4*)&part[((size_t)0 * NROW + row) * WJ + j0];
        #pragma unroll
        for (int sl = 1; sl < KS; ++sl) {
            const float4 p = *(const float4*)&part[((size_t)sl * NROW + row) * WJ + j0];
            s.x += p.x; s.y += p.y; s.z += p.z; s.w += p.w;
        }
        *(float4*)&AB[(size_t)row * 32 + j0] = s;
    } else {
        const int b = blk - 20;
        if (t < C) {
            const int c = t;
            float run = 0.f;
            #pragma unroll 4
            for (int n = 0; n < N; ++n) {
                const int row = b * N + n;
                float tv = part[((size_t)0 * NROW + row) * WJ + 32 + c]
                         + part[((size_t)1 * NROW + row) * WJ + 32 + c]
                         + part[((size_t)2 * NROW + row) * WJ + 32 + c]
                         + part[((size_t)3 * NROW + row) * WJ + 32 + c];
                run += tv;
                S[(size_t)row * C + c] = run;
            }
        }
    }
}

// ---------------------------------------------------------------------------
// K4: logits[b,i,k,c] = cand ? A[i,c] + B[k,c] + (S[k,c]-S[i-1,c])/(k-i+1) + bc : 0
// ---------------------------------------------------------------------------
__global__ __launch_bounds__(256) void finalize_kernel(
    const float* __restrict__ AB,
    const float* __restrict__ S,
    const float* __restrict__ bc,
    const int*   __restrict__ token_length,
    float4* __restrict__ out)
{
    const int idx = blockIdx.x * 256 + threadIdx.x;   // quad index
    const int q     = idx & 3;
    const int rest  = idx >> 2;
    const int k     = rest % N;
    const int rest2 = rest / N;
    const int i     = rest2 % N;
    const int b     = rest2 / N;

    const int tl = token_length[b];
    const bool cand = (i <= k) & (i < tl) & (k < tl);

    float4 v = {0.f, 0.f, 0.f, 0.f};
    if (cand) {
        const int co = q * 4;
        const float4 a  = *(const float4*)&AB[(size_t)(b * N + i) * 32 + co];
        const float4 bb = *(const float4*)&AB[(size_t)(b * N + k) * 32 + 16 + co];
        const float4 sk = *(const float4*)&S[(size_t)(b * N + k) * C + co];
        float4 si = {0.f, 0.f, 0.f, 0.f};
        if (i > 0) si = *(const float4*)&S[(size_t)(b * N + i - 1) * C + co];
        const float4 bcv = *(const float4*)&bc[co];
        const float inv = 1.0f / (float)(k - i + 1);
        v.x = a.x + bb.x + (sk.x - si.x) * inv + bcv.x;
        v.y = a.y + bb.y + (sk.y - si.y) * inv + bcv.y;
        v.z = a.z + bb.z + (sk.z - si.z) * inv + bcv.z;
        v.w = a.w + bb.w + (sk.w - si.w) * inv + bcv.w;
    }
    out[idx] = v;
}

extern "C" void kernel_launch(void* const* d_in, const int* in_sizes, int n_in,
                              void* d_out, int out_size, void* d_ws, size_t ws_size,
                              hipStream_t stream) {
    const float* TO   = (const float*)d_in[0];
    const float* Wd   = (const float*)d_in[1];
    const float* bd   = (const float*)d_in[2];
    const float* Wc   = (const float*)d_in[3];
    const float* bc   = (const float*)d_in[4];
    const int*   wm   = (const int*)d_in[5];
    const int*   tokl = (const int*)d_in[6];
    const int*   len  = (const int*)d_in[7];

    float* ws    = (float*)d_ws;
    float* hs_s  = ws;                               // 640*784 = 501760
    float* Wfull = hs_s + (size_t)NROW * KP;         // 784*48  = 37632
    float* part  = Wfull + (size_t)KP * WJ;          // 4*640*48 = 122880
    float* AB    = part + (size_t)KS * NROW * WJ;    // 640*32  = 20480
    float* S     = AB + (size_t)NROW * 32;           // 640*16  = 10240
    // ~2.8 MB total; every element written before read on every call.

    prep_kernel<<<NROW + 49, 256, 0, stream>>>(TO, Wd, bd, Wc, wm, len, hs_s, Wfull);
    gemm_kernel<<<dim3(KS, NROW / 8), 384, 0, stream>>>(hs_s, Wfull, tokl, part);
    reduce_scan_kernel<<<24, 256, 0, stream>>>(part, AB, S);
    finalize_kernel<<<(B * N * N * C / 4) / 256, 256, 0, stream>>>(AB, S, bc, tokl, (float4*)d_out);
}

// Round 4
// 35.686 us; speedup vs baseline: 1.5017x; 1.5017x over previous
//
#include <hip/hip_runtime.h>

#define B 4
#define L 200
#define N 160
#define HS 768
#define HD 256
#define C 16

#define KP 784            // padded K: 768 data + 1 gate(bias) + 15 zero
#define WJ 48             // fused cols: A(16) | B(16) | T(16)
#define KS 4              // split-k slices
#define KSL (KP / KS)     // 196
#define NROW (B * N)      // 640

// ---------------------------------------------------------------------------
// K1  blocks 0..639   : hs_s[row,0:768] = (sum TO rows for word n)/cnt,
//                       hs_s[row,768] = (cnt>0), hs_s[row,769:784] = 0
//     blocks 640..688 : Wfull[k,j] = Wd[k,:] @ Wc-block(j)  (Wc staged in LDS)
//                       row 768 = bd @ Wc-blocks, rows 769..783 = 0
// ---------------------------------------------------------------------------
__global__ __launch_bounds__(256) void prep_kernel(
    const float* __restrict__ TO,      // [B, L+1, HS]
    const float* __restrict__ Wd,      // [HS, HD]
    const float* __restrict__ bd,      // [HD]
    const float* __restrict__ Wc,      // [3*HD, C]
    const int*   __restrict__ wm,      // [B, L]
    const int*   __restrict__ lengths, // [B]
    float* __restrict__ hs_s,          // [NROW, KP]
    float* __restrict__ Wfull)         // [KP, WJ]
{
    const int blk = blockIdx.x;
    const int t = threadIdx.x;

    if (blk < NROW) {
        const int row = blk;
        const int b = row / N, n = row % N;
        const int len = lengths[b];
        const int* map = wm + b * L;

        int lo = 0, hi = L;
        while (lo < hi) { int m = (lo + hi) >> 1; if (map[m] < n) lo = m + 1; else hi = m; }
        int lo2 = lo, hi2 = L;
        while (lo2 < hi2) { int m = (lo2 + hi2) >> 1; if (map[m] < n + 1) lo2 = m + 1; else hi2 = m; }
        const int start = lo < len ? lo : len;
        const int stop  = lo2 < len ? lo2 : len;
        const int cnt   = stop - start;
        const float ci  = (cnt > 0) ? 1.0f / (float)cnt : 0.0f;

        float a0 = 0.f, a1 = 0.f, a2 = 0.f;
        const float* base = TO + ((size_t)b * (L + 1) + 1) * HS;
        for (int l = start; l < stop; ++l) {
            const float* r = base + (size_t)l * HS;
            a0 += r[t]; a1 += r[t + 256]; a2 += r[t + 512];
        }
        float* hr = hs_s + (size_t)row * KP;
        hr[t] = a0 * ci; hr[t + 256] = a1 * ci; hr[t + 512] = a2 * ci;
        if (t < 16) hr[768 + t] = (t == 0 && cnt > 0) ? 1.0f : 0.0f;
    } else {
        __shared__ float wc[3 * HD * C];              // 48 KiB, whole Wc
        for (int e = t; e < 3 * HD * C; e += 256) wc[e] = Wc[e];
        __syncthreads();

        const int wb = blk - NROW;                    // 0..48
        const int kl = t >> 4, c = t & 15;
        if (wb < 48) {
            const int k = wb * 16 + kl;
            const float4* wd4 = (const float4*)(Wd + (size_t)k * HD);
            float acc0 = 0.f, acc1 = 0.f, acc2 = 0.f;
            #pragma unroll 8
            for (int q = 0; q < HD / 4; ++q) {
                const float4 w = wd4[q];
                const int d = 4 * q;
                acc0 += w.x * wc[(d) * C + c]              + w.y * wc[(d + 1) * C + c]
                      + w.z * wc[(d + 2) * C + c]          + w.w * wc[(d + 3) * C + c];
                acc1 += w.x * wc[(HD + d) * C + c]         + w.y * wc[(HD + d + 1) * C + c]
                      + w.z * wc[(HD + d + 2) * C + c]     + w.w * wc[(HD + d + 3) * C + c];
                acc2 += w.x * wc[(2 * HD + d) * C + c]     + w.y * wc[(2 * HD + d + 1) * C + c]
                      + w.z * wc[(2 * HD + d + 2) * C + c] + w.w * wc[(2 * HD + d + 3) * C + c];
            }
            float* wr = Wfull + (size_t)k * WJ;
            wr[c] = acc0; wr[16 + c] = acc1; wr[32 + c] = acc2;
        } else {
            // bias row 768: bd . Wc-block, rows 769..783: zero
            if (t < WJ) {
                const int m = t >> 4, cc = t & 15;
                const float4* bd4 = (const float4*)bd;
                float acc = 0.f;
                #pragma unroll 8
                for (int q = 0; q < HD / 4; ++q) {
                    const float4 w = bd4[q];
                    const int d = 4 * q;
                    acc += w.x * wc[(m * HD + d) * C + cc]     + w.y * wc[(m * HD + d + 1) * C + cc]
                         + w.z * wc[(m * HD + d + 2) * C + cc] + w.w * wc[(m * HD + d + 3) * C + cc];
                }
                Wfull[(size_t)768 * WJ + t] = acc;
            }
            for (int idx = t; idx < 15 * WJ; idx += 256)
                Wfull[(size_t)769 * WJ + idx] = 0.f;
        }
    }
}

// ---------------------------------------------------------------------------
// K2: split-k GEMM  part[s,row,j] = sum_{k in slice s} hs_s[row,k] * Wfull[k,j]
//     T cols (j>=32) gated by token mask. 192 thr = 48 j x 4 rows, 640 blocks.
// ---------------------------------------------------------------------------
__global__ __launch_bounds__(192) void gemm_kernel(
    const float* __restrict__ hs_s,    // [NROW, KP]
    const float* __restrict__ Wfull,   // [KP, WJ]
    const int*   __restrict__ token_length,
    float* __restrict__ part)          // [KS, NROW, WJ]
{
    const int t  = threadIdx.x;
    const int tj = t % WJ;
    const int tr = t / WJ;                       // 0..3
    const int row = blockIdx.y * 4 + tr;
    const int k0  = blockIdx.x * KSL;

    const float* in = hs_s + (size_t)row * KP + k0;
    const float* wf = Wfull + (size_t)k0 * WJ + tj;

    float acc = 0.f;
    #pragma unroll 7
    for (int q = 0; q < KSL / 4; ++q) {
        const float4 v = *(const float4*)(in + 4 * q);
        acc += v.x * wf[(size_t)(4 * q) * WJ]     + v.y * wf[(size_t)(4 * q + 1) * WJ]
             + v.z * wf[(size_t)(4 * q + 2) * WJ] + v.w * wf[(size_t)(4 * q + 3) * WJ];
    }
    const int b = row / N, n = row % N;
    if (tj >= 32 && n >= token_length[b]) acc = 0.f;
    part[((size_t)blockIdx.x * NROW + row) * WJ + tj] = acc;
}

// ---------------------------------------------------------------------------
// K3: per (b, i-tile of 8): reduce split-k partials into LDS, blocked scan of
//     T -> S, emit logits tile with coalesced float4 stores.
// ---------------------------------------------------------------------------
__global__ __launch_bounds__(256) void finalize_kernel(
    const float* __restrict__ part,    // [KS, NROW, WJ]
    const float* __restrict__ bc,      // [C]
    const int*   __restrict__ token_length,
    float4* __restrict__ out)          // [B*N*N*C/4]
{
    const int it = blockIdx.x;         // 0..19
    const int b  = blockIdx.y;         // 0..3
    const int t  = threadIdx.x;
    const int tl = token_length[b];

    __shared__ float sBT[N * 32];      // [n][j2]: j2 0..15 = B, 16..31 = T
    __shared__ float sA[8 * 16];
    __shared__ float sS[(N + 1) * 16]; // inclusive cumsum, sS[0..15] = 0
    __shared__ float pref[16 * 16];

    // reduce B,T cols (j = 16..47) over 4 slices
    for (int e = t; e < N * 32; e += 256) {
        const int n = e >> 5, j2 = e & 31;
        const size_t base = ((size_t)b * N + n) * WJ + 16 + j2;
        sBT[e] = part[base]
               + part[(size_t)1 * NROW * WJ + base]
               + part[(size_t)2 * NROW * WJ + base]
               + part[(size_t)3 * NROW * WJ + base];
    }
    // reduce A cols for this block's 8 i-rows
    if (t < 128) {
        const int il = t >> 4, c = t & 15;
        const size_t base = ((size_t)b * N + it * 8 + il) * WJ + c;
        sA[t] = part[base]
              + part[(size_t)1 * NROW * WJ + base]
              + part[(size_t)2 * NROW * WJ + base]
              + part[(size_t)3 * NROW * WJ + base];
    }
    if (t < 16) sS[t] = 0.f;
    __syncthreads();

    // blocked scan over n of sBT[n][16+c] -> sS[(n+1)*16+c]
    const int c = t & 15, g = t >> 4;            // 16 chunks of 10
    {
        float run = 0.f;
        const int nb = g * 10;
        for (int u = 0; u < 10; ++u) {
            run += sBT[(nb + u) * 32 + 16 + c];
            sS[(nb + u + 1) * 16 + c] = run;
        }
        pref[g * 16 + c] = run;
    }
    __syncthreads();
    if (t < 16) {
        float off = 0.f;
        for (int g2 = 0; g2 < 16; ++g2) {
            const float tmp = pref[g2 * 16 + t];
            pref[g2 * 16 + t] = off;
            off += tmp;
        }
    }
    __syncthreads();
    {
        const float off = pref[g * 16 + c];
        const int nb = g * 10;
        for (int u = 0; u < 10; ++u) sS[(nb + u + 1) * 16 + c] += off;
    }
    __syncthreads();

    // emit: 8 i x 160 k x 4 c-quads = 5120 quads, 20 per thread
    for (int q = 0; q < 20; ++q) {
        const int qid = t + q * 256;
        const int cq  = qid & 3;
        const int k   = (qid >> 2) % N;
        const int il  = (qid >> 2) / N;          // 0..7
        const int i   = it * 8 + il;

        float4 v = {0.f, 0.f, 0.f, 0.f};
        if ((i <= k) & (i < tl) & (k < tl)) {
            const float4 a   = *(const float4*)&sA[il * 16 + cq * 4];
            const float4 bb  = *(const float4*)&sBT[k * 32 + cq * 4];
            const float4 sk  = *(const float4*)&sS[(k + 1) * 16 + cq * 4];
            const float4 si  = *(const float4*)&sS[i * 16 + cq * 4];
            const float4 bcq = *(const float4*)&bc[cq * 4];
            const float inv = 1.0f / (float)(k - i + 1);
            v.x = a.x + bb.x + (sk.x - si.x) * inv + bcq.x;
            v.y = a.y + bb.y + (sk.y - si.y) * inv + bcq.y;
            v.z = a.z + bb.z + (sk.z - si.z) * inv + bcq.z;
            v.w = a.w + bb.w + (sk.w - si.w) * inv + bcq.w;
        }
        out[((size_t)(b * N + i) * N + k) * 4 + cq] = v;
    }
}

extern "C" void kernel_launch(void* const* d_in, const int* in_sizes, int n_in,
                              void* d_out, int out_size, void* d_ws, size_t ws_size,
                              hipStream_t stream) {
    const float* TO   = (const float*)d_in[0];
    const float* Wd   = (const float*)d_in[1];
    const float* bd   = (const float*)d_in[2];
    const float* Wc   = (const float*)d_in[3];
    const float* bc   = (const float*)d_in[4];
    const int*   wm   = (const int*)d_in[5];
    const int*   tokl = (const int*)d_in[6];
    const int*   len  = (const int*)d_in[7];

    float* ws    = (float*)d_ws;
    float* hs_s  = ws;                               // 640*784
    float* Wfull = hs_s + (size_t)NROW * KP;         // 784*48
    float* part  = Wfull + (size_t)KP * WJ;          // 4*640*48
    // ~2.65 MB total; every element written before read on every call.

    prep_kernel<<<NROW + 49, 256, 0, stream>>>(TO, Wd, bd, Wc, wm, len, hs_s, Wfull);
    gemm_kernel<<<dim3(KS, NROW / 4), 192, 0, stream>>>(hs_s, Wfull, tokl, part);
    finalize_kernel<<<dim3(20, B), 256, 0, stream>>>(part, bc, tokl, (float4*)d_out);
}